// Round 1
// baseline (1129.519 us; speedup 1.0000x reference)
//
#include <hip/hip_runtime.h>

// Problem constants: B=32, T=256, IN=64, D=128
// Outputs (fp32, concatenated): h_final[32,128] | y[32,256,128] | jacs[256,32,128,128] | dh_dWh[32,128,128,128]
// out offsets: 0, 4096, 1052672, 135270400  (total 202379264)

#define JACOFF 1052672L
#define DHWOFF 135270400L

typedef __attribute__((ext_vector_type(8))) short frag_ab;   // 8 bf16 (4 VGPRs)
typedef __attribute__((ext_vector_type(4))) float frag_cd;   // 4 fp32

__device__ __forceinline__ short f2bf(float f) {
    unsigned u = __builtin_bit_cast(unsigned, f);
    unsigned r = (u + 0x7fffu + ((u >> 16) & 1u)) >> 16;     // RNE
    return (short)r;
}

// Raw workgroup barrier: LDS ordering only. __syncthreads() would emit
// s_waitcnt vmcnt(0) before s_barrier, draining the per-step global
// stores (Abf/wgv/wc/y) and the xw prefetch load on the serial scan
// critical path. All global traffic in the loop is thread-private, so
// lgkmcnt(0) (abuf/hbuf visibility) is sufficient.
__device__ __forceinline__ void wg_barrier() {
    asm volatile("s_waitcnt lgkmcnt(0)\n\ts_barrier" ::: "memory");
}

// quad_perm DPP butterfly adds (lane groups of 4 are quad-aligned: tid = i*4+qtr)
__device__ __forceinline__ float dpp_xor1(float x) {
    int r = __builtin_amdgcn_mov_dpp(__builtin_bit_cast(int, x), 0xB1, 0xF, 0xF, true); // [1,0,3,2]
    return __builtin_bit_cast(float, r);
}
__device__ __forceinline__ float dpp_xor2(float x) {
    int r = __builtin_amdgcn_mov_dpp(__builtin_bit_cast(int, x), 0x4E, 0xF, 0xF, true); // [2,3,0,1]
    return __builtin_bit_cast(float, r);
}

// ---------- prep (blocks 0..127): transpose Wh, Wgate ; xw (blocks 128+): x@Wx ----------
__global__ __launch_bounds__(256) void prep_xw_kernel(
    const float* __restrict__ Wh, const float* __restrict__ Wg,
    const float* __restrict__ x, const float* __restrict__ Wx,
    float* __restrict__ whT, float* __restrict__ wgT, float* __restrict__ xw)
{
    int blk = blockIdx.x;
    int tid = threadIdx.x;
    if (blk < 128) {
        int idx = blk * 256 + tid;               // 0..32767
        if (idx < 16384) {                       // WhT[i][k] = Wh[k][i]
            int k = idx >> 7, i = idx & 127;
            whT[i * 128 + k] = Wh[idx];
        } else {                                 // WgT[i][k] = Wgate[k][i]
            int r = idx - 16384;
            int k = r >> 7, i = r & 127;
            wgT[i * 128 + k] = Wg[r];
        }
        return;
    }
    // xw path: 2 (b,t) rows per block
    __shared__ float xs[2][64];
    int sub = tid >> 7;                          // 0/1
    int bt = (blk - 128) * 2 + sub;
    int i = tid & 127;
    if (i < 64) xs[sub][i] = x[bt * 64 + i];
    __syncthreads();
    float acc = 0.f;
#pragma unroll
    for (int m = 0; m < 64; ++m)
        acc += xs[sub][m] * Wx[m * 128 + i];     // Wx row: coalesced across i, L1-hot
    xw[bt * 128 + i] = acc;
}

// ---------- scan (blocks 0..31, 512 thr, 4-way k-split) + pk (blocks 32..543) fused ----------
// scan: thread (i = tid>>2, qtr = tid&3) computes a 32-wide partial dot; combine via
//   DPP quad_perm xor1+xor2 (lane groups of 4 are quad-aligned).
// pk: PT[col][k] = bf16(Wgate[k][i] * Wh[j][k]), col = i*128+j. 32 cols/block @512 thr.
__global__ __launch_bounds__(512, 1) void scan_pk_kernel(
    const float* __restrict__ xw, const float* __restrict__ h0,
    const float* __restrict__ whT, const float* __restrict__ wgT,
    const float* __restrict__ Wgate, const float* __restrict__ Wh,
    float* __restrict__ out,
    short* __restrict__ Abf, float* __restrict__ wgv, float* __restrict__ wc,
    float* __restrict__ wdF, float* __restrict__ wuF, float* __restrict__ whF,
    short* __restrict__ PT)
{
    int tid = threadIdx.x;
    if (blockIdx.x >= 32) {
        // ---- pk path ----
        int c = (blockIdx.x - 32) * 32 + (tid >> 4);
        int k0 = (tid & 15) * 8;
        int i = c >> 7, j = c & 127;
        short v[8];
#pragma unroll
        for (int m = 0; m < 8; ++m) {
            float wg = Wgate[(k0 + m) * 128 + i];
            float wh = Wh[j * 128 + k0 + m];
            v[m] = f2bf(wg * wh);
        }
        *(frag_ab*)(PT + (long)c * 128 + k0) = *(frag_ab*)v;
        return;
    }

    // ---- scan path ----
    const int b = blockIdx.x;
    const int i = tid >> 2, qtr = tid & 3;
    __shared__ float hbuf[2][128];
    __shared__ float abuf[128];
    float wh[32], wgc[32];
    {
        const float* whr = whT + i * 128 + qtr * 32;   // quarter of column i of Wh
        const float* wgr = wgT + i * 128 + qtr * 32;
#pragma unroll
        for (int k = 0; k < 32; k += 4) {
            float4 a4 = *(const float4*)(whr + k);
            wh[k] = a4.x; wh[k + 1] = a4.y; wh[k + 2] = a4.z; wh[k + 3] = a4.w;
            float4 b4 = *(const float4*)(wgr + k);
            wgc[k] = b4.x; wgc[k + 1] = b4.y; wgc[k + 2] = b4.z; wgc[k + 3] = b4.w;
        }
    }
    if (qtr == 0) hbuf[0][i] = h0[b * 128 + i];
    __syncthreads();

    const float inv_sqrt2 = 0.70710678118654752f;
    const float inv_sqrt2pi = 0.39894228040143268f;

    // distance-2 xw prefetch pipeline: loads never get drained by a barrier
    // now, but the consumer-side s_waitcnt needs ~2 phases of slack to cover
    // LLC latency (xw was written by a previous dispatch -> not in local L2).
    float xwv = xw[(b * 256 + 0) * 128 + i];
    float xw1 = xw[(b * 256 + 1) * 128 + i];

    for (int t = 0; t < 256; ++t) {
        int p = t & 1;
        int tn = (t < 254) ? t + 2 : 255;
        float xw2 = xw[(b * 256 + tn) * 128 + i];

        float s0 = 0.f, s1 = 0.f, s2 = 0.f, s3 = 0.f;
        const float* hb = &hbuf[p][qtr * 32];
#pragma unroll
        for (int k = 0; k < 32; k += 4) {
            float4 h4 = *(const float4*)(hb + k);
            s0 += h4.x * wh[k];
            s1 += h4.y * wh[k + 1];
            s2 += h4.z * wh[k + 2];
            s3 += h4.w * wh[k + 3];
        }
        float s = (s0 + s1) + (s2 + s3);
        s += dpp_xor1(s);
        s += dpp_xor2(s);
        float pre = xwv + s;

        float cdf = 0.5f * (1.0f + erff(pre * inv_sqrt2));
        float a = pre * cdf;                                   // exact gelu
        float dval = cdf + pre * inv_sqrt2pi * expf(-0.5f * pre * pre);  // gelu'

        long tb = (long)(t * 32 + b) * 128 + i;
        if (qtr == 0) {
            Abf[tb] = f2bf(dval);
            abuf[i] = a;
        }
        wg_barrier();                                          // (1) abuf visible

        float r0 = 0.f, r1 = 0.f, r2 = 0.f, r3 = 0.f;
        const float* ab = &abuf[qtr * 32];
#pragma unroll
        for (int k = 0; k < 32; k += 4) {
            float4 a4 = *(const float4*)(ab + k);
            r0 += a4.x * wgc[k];
            r1 += a4.y * wgc[k + 1];
            r2 += a4.z * wgc[k + 2];
            r3 += a4.w * wgc[k + 3];
        }
        float r = (r0 + r1) + (r2 + r3);
        r += dpp_xor1(r);
        r += dpp_xor2(r);
        float g = 1.0f / (1.0f + expf(-r));
        float hp = hbuf[p][i];
        float c = (hp - 1.0f) * g * (1.0f - g);
        float hn = g * hp + 1.0f - g;
        if (qtr == 0) {
            hbuf[p ^ 1][i] = hn;
            wgv[tb] = g;
            wc[tb] = c;
            out[4096 + (b * 256 + t) * 128 + i] = hn;          // y
        }
        xwv = xw1; xw1 = xw2;
        wg_barrier();                                          // (2) new h visible
    }

    float hfin = hbuf[0][i];                                   // T even -> final state in buf 0
    if (qtr == 0) {
        out[b * 128 + i] = hfin;                               // h_final
        whF[b * 128 + i] = hfin;
    }

    // extra evaluation at (x_last, h_final) for dh_dWh
    {
        float s0 = 0.f, s1 = 0.f, s2 = 0.f, s3 = 0.f;
        const float* hb = &hbuf[0][qtr * 32];
#pragma unroll
        for (int k = 0; k < 32; k += 4) {
            float4 h4 = *(const float4*)(hb + k);
            s0 += h4.x * wh[k];
            s1 += h4.y * wh[k + 1];
            s2 += h4.z * wh[k + 2];
            s3 += h4.w * wh[k + 3];
        }
        float s = (s0 + s1) + (s2 + s3);
        s += dpp_xor1(s);
        s += dpp_xor2(s);
        float pre = xwv + s;                                   // xwv == xw[b, 255]
        float cdf = 0.5f * (1.0f + erff(pre * inv_sqrt2));
        float a = pre * cdf;
        float dval = cdf + pre * inv_sqrt2pi * expf(-0.5f * pre * pre);
        if (qtr == 0) {
            wdF[b * 128 + i] = dval;
            abuf[i] = a;
        }
        __syncthreads();
        float r0 = 0.f, r1 = 0.f, r2 = 0.f, r3 = 0.f;
        const float* ab = &abuf[qtr * 32];
#pragma unroll
        for (int k = 0; k < 32; k += 4) {
            float4 a4 = *(const float4*)(ab + k);
            r0 += a4.x * wgc[k];
            r1 += a4.y * wgc[k + 1];
            r2 += a4.z * wgc[k + 2];
            r3 += a4.w * wgc[k + 3];
        }
        float r = (r0 + r1) + (r2 + r3);
        r += dpp_xor1(r);
        r += dpp_xor2(r);
        float g = 1.0f / (1.0f + expf(-r));
        if (qtr == 0) wuF[b * 128 + i] = (hfin - 1.0f) * g * (1.0f - g);
    }
}

// ---------- jacmm (+ fused dhdw): 12288 blocks, pattern [jac,jac,dhdw] ----------
// jac: C[row=tb][col=i*128+j] = sum_k Abf[row][k] * PT[col][k]; epilogue scale+diag.
// Both Abf and PT are k-major == exactly the 16x16x32 MFMA fragment layout, so
// fragments are loaded DIRECTLY from global (L2/LLC-resident: 6 MB working set).
// No LDS staging, no barrier, no 64 KB LDS occupancy cap.
// dhdw: dh_dWh[b,i,p,q] = u[b,i] * hF[b,p] * dF[b,q] * Wgate[q,i]
__global__ __launch_bounds__(256) void jacmm_dhdw_kernel(
    const short* __restrict__ Abf,   // [8192][128] bf16
    const short* __restrict__ PT,    // [16384][128] bf16
    const float* __restrict__ wgv,   // [8192][128]
    const float* __restrict__ wc,    // [8192][128]
    const float* __restrict__ Wgate,
    const float* __restrict__ dF, const float* __restrict__ uF, const float* __restrict__ hF,
    float* __restrict__ out)
{
    int bx = blockIdx.x;
    int tid = threadIdx.x;
    int grp = bx / 3, rem = bx % 3;

    if (rem == 2) {
        // ---- dhdw path: unit = grp (0..4095) = b*128 + i ----
        __shared__ float hs[128], dsh[128];
        int b = grp >> 7, i = grp & 127;
        if (tid < 128) {
            hs[tid] = hF[b * 128 + tid];
            dsh[tid] = dF[b * 128 + tid];
        }
        __syncthreads();
        float u = uF[b * 128 + i];
        int q0 = (tid & 31) * 4, p0 = (tid >> 5) * 16;
        float w0 = u * dsh[q0 + 0] * Wgate[(q0 + 0) * 128 + i];
        float w1 = u * dsh[q0 + 1] * Wgate[(q0 + 1) * 128 + i];
        float w2 = u * dsh[q0 + 2] * Wgate[(q0 + 2) * 128 + i];
        float w3 = u * dsh[q0 + 3] * Wgate[(q0 + 3) * 128 + i];
        float* dst = out + DHWOFF + (long)grp * 16384;
#pragma unroll
        for (int pp = 0; pp < 16; ++pp) {
            float hp = hs[p0 + pp];
            *(float4*)(dst + (p0 + pp) * 128 + q0) = make_float4(hp * w0, hp * w1, hp * w2, hp * w3);
        }
        return;
    }

    // ---- jac path: tile index = grp*2 + rem (0..8191) ----
    int jb = grp * 2 + rem;
    int rb = jb & 63;        // row block: tb in [rb*128, rb*128+128)
    int cb = jb >> 6;        // col block = i (0..127)

    const short* Ag = Abf + (long)rb * (128 * 128);
    const short* Bg = PT + (long)cb * (128 * 128);

    int w = tid >> 6;            // wave 0..3
    int lane = tid & 63;
    int wr = w >> 1;             // wave row half
    int wcol = w & 1;            // wave col half
    int lrow = lane & 15;
    int quad = lane >> 4;

    // prefetch epilogue gathers early (hide ~200-900 cyc latency under MFMA)
    long rowbase = (long)rb * 128;
    float ci[4][4], gi[4][4];
#pragma unroll
    for (int p = 0; p < 4; ++p) {
        int trow0 = wr * 64 + p * 16 + quad * 4;
#pragma unroll
        for (int reg = 0; reg < 4; ++reg) {
            long row = rowbase + trow0 + reg;
            ci[p][reg] = wc[row * 128 + cb];
            gi[p][reg] = wgv[row * 128 + cb];
        }
    }

    frag_cd acc[4][4];
#pragma unroll
    for (int p = 0; p < 4; ++p)
#pragma unroll
        for (int q = 0; q < 4; ++q) {
            acc[p][q][0] = 0.f; acc[p][q][1] = 0.f; acc[p][q][2] = 0.f; acc[p][q][3] = 0.f;
        }

#pragma unroll
    for (int kk = 0; kk < 4; ++kk) {     // k-chunks of 32
        int ko8 = (kk * 4 + quad) * 8;   // this lane's k-octet byte... element offset
        frag_ab af[4], bf[4];
#pragma unroll
        for (int p = 0; p < 4; ++p) {
            int r = wr * 64 + p * 16 + lrow;
            af[p] = *(const frag_ab*)(Ag + r * 128 + ko8);
        }
#pragma unroll
        for (int q = 0; q < 4; ++q) {
            int n = wcol * 64 + q * 16 + lrow;
            bf[q] = *(const frag_ab*)(Bg + n * 128 + ko8);
        }
#pragma unroll
        for (int p = 0; p < 4; ++p)
#pragma unroll
            for (int q = 0; q < 4; ++q)
                acc[p][q] = __builtin_amdgcn_mfma_f32_16x16x32_bf16(af[p], bf[q], acc[p][q], 0, 0, 0);
    }

    // epilogue: C/D layout col = lane&15, row = quad*4 + reg
#pragma unroll
    for (int p = 0; p < 4; ++p) {
        int trow0 = wr * 64 + p * 16 + quad * 4;
#pragma unroll
        for (int reg = 0; reg < 4; ++reg) {
            long row = rowbase + trow0 + reg;
            float* orow = out + JACOFF + row * 16384 + (long)cb * 128;
#pragma unroll
            for (int q = 0; q < 4; ++q) {
                int tcol = wcol * 64 + q * 16 + lrow;
                float v = ci[p][reg] * acc[p][q][reg];
                if (tcol == cb) v += gi[p][reg];
                orow[tcol] = v;
            }
        }
    }
}

extern "C" void kernel_launch(void* const* d_in, const int* in_sizes, int n_in,
                              void* d_out, int out_size, void* d_ws, size_t ws_size,
                              hipStream_t stream)
{
    (void)in_sizes; (void)n_in; (void)out_size; (void)ws_size;
    const float* x     = (const float*)d_in[0];
    const float* h0    = (const float*)d_in[1];
    const float* Wx    = (const float*)d_in[2];
    const float* Wgate = (const float*)d_in[3];
    const float* Wh    = (const float*)d_in[4];
    float* out = (float*)d_out;
    float* ws  = (float*)d_ws;

    // workspace layout (floats), ~19 MB total, no aliasing (pk runs concurrently with scan)
    float* xw  = ws;                         // 1048576  [b][t][i]
    float* whT = ws + 1048576;               // 16384
    float* wgT = ws + 1064960;               // 16384
    float* wgv = ws + 1081344;               // 1048576  [t*32+b][i]
    float* wc  = ws + 2129920;               // 1048576
    float* wdF = ws + 3178496;               // 4096
    float* wuF = ws + 3182592;               // 4096
    float* whF = ws + 3186688;               // 4096
    short* Abf = (short*)(ws + 3190784);     // 1048576 bf16 (524288 floats) [t*32+b][k]
    short* PT  = (short*)(ws + 3715072);     // 2097152 bf16 (1048576 floats) [col][k]

    prep_xw_kernel<<<4224, 256, 0, stream>>>(Wh, Wgate, x, Wx, whT, wgT, xw);
    scan_pk_kernel<<<544, 512, 0, stream>>>(xw, h0, whT, wgT, Wgate, Wh, out,
                                            Abf, wgv, wc, wdF, wuF, whF, PT);
    jacmm_dhdw_kernel<<<12288, 256, 0, stream>>>(Abf, PT, wgv, wc, Wgate, wdF, wuF, whF, out);
}